// Round 1
// baseline (76.061 us; speedup 1.0000x reference)
//
#include <hip/hip_runtime.h>
#include <math.h>

#define VOX 64
#define NPOLY 32
#define NEDGE 32
#define NEDGES_TOT (NPOLY * NEDGE)      // 1024
#define GROUPS 4
#define POLY_PER_GROUP (NPOLY / GROUPS) // 8

// block = 256 threads = 64 pixels (one image row) x 4 polygon-groups
// grid  = B * 64 rows = 512 blocks
__global__ __launch_bounds__(256, 2) void extrusion_kernel(
    const float* __restrict__ polygons,    // (B,32,32,2)
    const float* __restrict__ attributes,  // (B,4)
    const float* __restrict__ validity,    // (B,32)
    float* __restrict__ out)               // (B,64,64,64)
{
    __shared__ float4 eA[NEDGES_TOT];      // x0, y0, ex, ey
    __shared__ float4 eB[NEDGES_TOT];      // inv_norm2, slope, y1, pad
    __shared__ float  partial[GROUPS][VOX];
    __shared__ float  comb[VOX];
    __shared__ int    validF[NPOLY];

    const int t   = threadIdx.x;
    const int b   = blockIdx.x >> 6;   // batch
    const int row = blockIdx.x & 63;   // i (y index)
    const float py = (float)row * (1.0f / 63.0f);
    const float px = (float)(t & 63) * (1.0f / 63.0f);

    // stage validity flags (block-uniform per polygon)
    if (t < NPOLY) validF[t] = (validity[b * NPOLY + t] >= 0.5f) ? 1 : 0;

    // precompute edge constants: 4 edges per thread, coalesced float2 loads
    const float2* pb = (const float2*)(polygons + (size_t)b * NPOLY * NEDGE * 2);
    for (int e = t; e < NEDGES_TOT; e += 256) {
        int n  = e >> 5;
        int k  = e & 31;
        int k1 = (k + 1) & 31;
        float2 v0 = pb[n * NEDGE + k];
        float2 v1 = pb[n * NEDGE + k1];
        float ex = v1.x - v0.x;
        float ey = v1.y - v0.y;
        float inv   = 1.0f / (ex * ex + ey * ey + 1e-8f);
        float slope = ex / (ey + 1e-8f);          // (x1-x0)/(y1-y0+EPS)
        eA[e] = make_float4(v0.x, v0.y, ex, ey);
        eB[e] = make_float4(inv, slope, v1.y, 0.0f);
    }
    __syncthreads();

    const int g = t >> 6;              // polygon group == wave id
    float minsdf = 1e30f;
    for (int nn = 0; nn < POLY_PER_GROUP; ++nn) {
        int n = g * POLY_PER_GROUP + nn;
        if (!validF[n]) continue;      // wave-uniform branch
        float mind2  = 1e30f;
        int   parity = 0;
        int   base   = n * NEDGE;
        #pragma unroll 4
        for (int k = 0; k < NEDGE; ++k) {
            float4 A  = eA[base + k];  // wave-uniform address -> LDS broadcast
            float4 Bv = eB[base + k];
            float vx = px - A.x;
            float vy = py - A.y;
            float dot = vx * A.z + vy * A.w;
            float tt  = fminf(fmaxf(dot * Bv.x, 0.0f), 1.0f);  // v_med3
            float dx = vx - tt * A.z;
            float dy = vy - tt * A.w;
            float d2 = dx * dx + dy * dy;
            mind2 = fminf(mind2, d2);
            // crossing test: (y0<=py) XOR (y1<=py)  &&  inter_x > px
            bool a  = (A.y  <= py);
            bool bb = (Bv.z <= py);
            float ix = fmaf(Bv.y, vy, A.x);
            parity ^= ((a != bb) && (ix > px)) ? 1 : 0;
        }
        float d   = sqrtf(mind2);
        float sdf = parity ? -d : d;
        minsdf = fminf(minsdf, sdf);
    }
    partial[g][t & 63] = minsdf;
    __syncthreads();

    // reduce 4 groups -> sigmoid once (monotone: max sigmoid = sigmoid of min sdf)
    if (t < VOX) {
        float m = fminf(fminf(partial[0][t], partial[1][t]),
                        fminf(partial[2][t], partial[3][t]));
        // no valid polygon -> m = 1e30 -> expf(inf) -> 0  (matches reference's 0)
        comb[t] = 1.0f / (1.0f + __expf(100.0f * m));
    }
    __syncthreads();

    // depth mask: h = clip(floor(att0 * 64), 1, 64)
    float att = attributes[b * 4 + 0];
    int h = (int)floorf(att * 64.0f);
    h = max(1, min(64, h));

    // write all 64 z-slices, float4-coalesced; every output element is written
    float4* out4 = (float4*)out;
    const int q  = t & 15;             // float4 column within row (fixed per thread)
    const int zs = t >> 4;             // 0..15
    float4 cv = make_float4(comb[q * 4 + 0], comb[q * 4 + 1],
                            comb[q * 4 + 2], comb[q * 4 + 3]);
    float4 zero = make_float4(0.f, 0.f, 0.f, 0.f);
    size_t base4 = (size_t)b * 65536 + (size_t)row * 16 + q;   // /4 indexing
    #pragma unroll
    for (int it = 0; it < 4; ++it) {
        int z = it * 16 + zs;
        out4[base4 + (size_t)z * 1024] = (z < h) ? cv : zero;
    }
}

extern "C" void kernel_launch(void* const* d_in, const int* in_sizes, int n_in,
                              void* d_out, int out_size, void* d_ws, size_t ws_size,
                              hipStream_t stream) {
    const float* polygons   = (const float*)d_in[0];
    const float* attributes = (const float*)d_in[1];
    const float* validity   = (const float*)d_in[2];
    float* out = (float*)d_out;
    const int B = in_sizes[2] / NPOLY;   // 8
    dim3 grid(B * VOX);                  // 512 blocks
    dim3 block(256);
    extrusion_kernel<<<grid, block, 0, stream>>>(polygons, attributes, validity, out);
}

// Round 2
// 70.514 us; speedup vs baseline: 1.0787x; 1.0787x over previous
//
#include <hip/hip_runtime.h>
#include <math.h>

#define VOX 64
#define NPOLY 32
#define NEDGE 32
#define NET (NPOLY * NEDGE)   // 1024 edges

// block = 512 threads = 64 pixels (one row) x 8 polygon groups
// grid  = B * 64 rows = 512 blocks  ->  4096 waves = 4 waves/SIMD
__global__ __launch_bounds__(512, 2) void extrusion_kernel(
    const float* __restrict__ polygons,    // (B,32,32,2)
    const float* __restrict__ attributes,  // (B,4)
    const float* __restrict__ validity,    // (B,32)
    float* __restrict__ out)               // (B,64,64,64)
{
    __shared__ float4 ecA[NET];        // x0, ex, ey, inv_norm2
    __shared__ float4 ecB[NET];        // c1 = vy*ey, vy, ix (-inf if no y-cross), pad
    __shared__ float  partial[8][VOX];
    __shared__ float  comb[VOX];
    __shared__ int    vIdx[NPOLY];
    __shared__ int    nValidS;

    const int t   = threadIdx.x;
    const int b   = blockIdx.x >> 6;   // batch
    const int row = blockIdx.x & 63;   // y index
    const float py = (float)row * (1.0f / 63.0f);

    // ---- validity compaction: ballot + prefix popcount (first wave) ----
    if (t < 64) {
        bool f = (t < NPOLY) && (validity[b * NPOLY + t] >= 0.5f);
        unsigned long long m = __ballot(f);
        if (f) vIdx[__popcll(m & ((1ull << t) - 1ull))] = t;
        if (t == 0) nValidS = (int)__popcll(m);
    }

    // ---- per-row edge constants: 2 edges per thread ----
    const float2* pb = (const float2*)(polygons + (size_t)b * NET * 2);
    for (int e = t; e < NET; e += 512) {
        int n  = e >> 5;
        int k  = e & 31;
        int k1 = (k + 1) & 31;
        float2 v0 = pb[n * NEDGE + k];
        float2 v1 = pb[n * NEDGE + k1];
        float ex = v1.x - v0.x;
        float ey = v1.y - v0.y;
        float inv = 1.0f / (ex * ex + ey * ey + 1e-8f);
        float vy  = py - v0.y;
        float c1  = vy * ey;
        // y-crossing flag is row-uniform per edge; fold into ix sentinel
        bool ycross = ((v0.y <= py) && (v1.y > py)) || ((v1.y <= py) && (v0.y > py));
        float ix = ycross ? (v0.x + ex * (vy / (ey + 1e-8f))) : -1e30f;
        ecA[e] = make_float4(v0.x, ex, ey, inv);
        ecB[e] = make_float4(c1, vy, ix, 0.0f);
    }
    __syncthreads();

    // ---- SDF over compacted valid polygons, strided by group ----
    const int g  = t >> 6;             // wave id 0..7 (wave-uniform)
    const int lx = t & 63;             // pixel x
    const float px = (float)lx * (1.0f / 63.0f);
    const int nV = nValidS;
    float minsdf = 1e30f;
    for (int j = g; j < nV; j += 8) {
        int base = vIdx[j] * NEDGE;    // wave-uniform
        float mind2 = 1e30f;
        int cnt = 0;
        #pragma unroll
        for (int k = 0; k < NEDGE; ++k) {
            float4 A  = ecA[base + k]; // broadcast LDS read
            float4 Bc = ecB[base + k];
            float vx  = px - A.x;
            float dot = fmaf(vx, A.y, Bc.x);              // v.e = vx*ex + vy*ey
            float tt  = fminf(fmaxf(dot * A.w, 0.0f), 1.0f);
            float dx  = fmaf(-tt, A.y, vx);
            float dy  = fmaf(-tt, A.z, Bc.y);
            float d2  = fmaf(dy, dy, dx * dx);
            mind2 = fminf(mind2, d2);
            cnt += (Bc.z > px) ? 1 : 0;                   // crossing count
        }
        float d = sqrtf(mind2);
        minsdf = fminf(minsdf, (cnt & 1) ? -d : d);
    }
    partial[g][lx] = minsdf;
    __syncthreads();

    // ---- reduce 8 groups -> one sigmoid per pixel (sigmoid monotone) ----
    if (t < VOX) {
        float m = partial[0][t];
        #pragma unroll
        for (int gg = 1; gg < 8; ++gg) m = fminf(m, partial[gg][t]);
        // nV==0 -> m=1e30 -> expf(inf) -> comb=0 (matches reference)
        comb[t] = 1.0f / (1.0f + __expf(100.0f * m));
    }
    __syncthreads();

    // ---- extrusion epilogue: h = clip(floor(att0*64), 1, 64) ----
    float att = attributes[b * 4 + 0];
    int h = max(1, min(64, (int)floorf(att * 64.0f)));

    // write all 64 z-slices for this row; 2 float4 per thread, every elem written
    float4* out4 = (float4*)out;
    const int q  = t & 15;             // float4 column
    const int z0 = t >> 4;             // 0..31
    float4 cv = make_float4(comb[q * 4 + 0], comb[q * 4 + 1],
                            comb[q * 4 + 2], comb[q * 4 + 3]);
    float4 zero = make_float4(0.f, 0.f, 0.f, 0.f);
    size_t base4 = (size_t)b * 65536 + (size_t)row * 16 + q;  // /4 indexing
    out4[base4 + (size_t)z0 * 1024]        = (z0 < h)        ? cv : zero;
    out4[base4 + (size_t)(z0 + 32) * 1024] = ((z0 + 32) < h) ? cv : zero;
}

extern "C" void kernel_launch(void* const* d_in, const int* in_sizes, int n_in,
                              void* d_out, int out_size, void* d_ws, size_t ws_size,
                              hipStream_t stream) {
    const float* polygons   = (const float*)d_in[0];
    const float* attributes = (const float*)d_in[1];
    const float* validity   = (const float*)d_in[2];
    float* out = (float*)d_out;
    const int B = in_sizes[2] / NPOLY;   // 8
    dim3 grid(B * VOX);                  // 512 blocks
    dim3 block(512);
    extrusion_kernel<<<grid, block, 0, stream>>>(polygons, attributes, validity, out);
}